// Round 2
// baseline (539.750 us; speedup 1.0000x reference)
//
#include <hip/hip_runtime.h>
#include <math.h>

#define CIN  256
#define COUT 128
#define HH   64
#define WW_  64
#define HW   4096
#define NB   4
#define OCSPLIT 2

// ---------------- weight prep: w_t[c][co_grp*100 + co_in*12 + k] = w_dcn[co][c][k] * bn_scale[co]
__global__ __launch_bounds__(256) void k_prep_w(
    const float* __restrict__ w_dcn, const float* __restrict__ b_dcn,
    const float* __restrict__ gamma, const float* __restrict__ beta,
    const float* __restrict__ rmean, const float* __restrict__ rvar,
    float* __restrict__ w_t, float* __restrict__ bias_t)
{
  int t = blockIdx.x * 256 + threadIdx.x;
  if (t < COUT) {
    float sc = gamma[t] * rsqrtf(rvar[t] + 1e-5f);
    bias_t[t] = b_dcn[t] * sc + beta[t] - rmean[t] * sc;
  }
  if (t >= CIN * COUT * 9) return;
  int k = t % 9;
  int q = t / 9;
  int co = q % COUT;
  int c  = q / COUT;
  float sc = gamma[co] * rsqrtf(rvar[co] + 1e-5f);
  // padded layout: per c, 1600 floats; co group of 8 has stride 100 (breaks bank aliasing)
  w_t[(size_t)c * 1600 + (co >> 3) * 100 + (co & 7) * 12 + k] =
      w_dcn[((size_t)co * CIN + c) * 9 + k] * sc;
}

// ---------------- offset conv (27 ch, 3x3, pad 1), split over ci into OCSPLIT partials
__global__ __launch_bounds__(256) void k_off_conv(
    const float* __restrict__ x, const float* __restrict__ w_off,
    float* __restrict__ om_part)
{
  int blk = blockIdx.x;
  int split = blk & (OCSPLIT - 1);
  int bh = blk / OCSPLIT;
  int b = bh >> 6, h = bh & 63;
  int ci0 = split * (CIN / OCSPLIT);

  __shared__ float xs[8][3][66];
  __shared__ float wl[8][27][9];

  int t = threadIdx.x;
  int w = t & 63;        // lane = w  -> coalesced x reads, wave-uniform weights
  int slot = t >> 6;     // 4 slots, each handles co = slot, slot+4, ... (<27)

  float acc[7];
#pragma unroll
  for (int j = 0; j < 7; ++j) acc[j] = 0.f;

  const int NT = (CIN / OCSPLIT) / 8;
  for (int tile = 0; tile < NT; ++tile) {
    int cb = ci0 + tile * 8;
    __syncthreads();
    for (int j = t; j < 8 * 3 * 66; j += 256) {
      int ci = j / 198, rem = j - ci * 198;
      int r = rem / 66, wp = rem - r * 66;
      int hh = h + r - 1, ww = wp - 1;
      float v = 0.f;
      if (hh >= 0 && hh < 64 && (unsigned)ww < 64u)
        v = x[(((size_t)b * CIN + cb + ci) * 64 + hh) * 64 + ww];
      xs[ci][r][wp] = v;
    }
    for (int j = t; j < 8 * 27 * 9; j += 256) {
      int ci = j / 243, rem = j - ci * 243;
      int c2 = rem / 9, k = rem - c2 * 9;
      wl[ci][c2][k] = w_off[((size_t)c2 * CIN + cb + ci) * 9 + k];
    }
    __syncthreads();
#pragma unroll 1
    for (int ci = 0; ci < 8; ++ci) {
      float xv[3][3];
#pragma unroll
      for (int r = 0; r < 3; ++r)
#pragma unroll
        for (int d = 0; d < 3; ++d)
          xv[r][d] = xs[ci][r][w + d];
#pragma unroll
      for (int j = 0; j < 7; ++j) {
        int co = slot + 4 * j;
        if (co < 27) {
#pragma unroll
          for (int r = 0; r < 3; ++r)
#pragma unroll
            for (int d = 0; d < 3; ++d)
              acc[j] = fmaf(wl[ci][co][r * 3 + d], xv[r][d], acc[j]);
        }
      }
    }
  }
#pragma unroll
  for (int j = 0; j < 7; ++j) {
    int co = slot + 4 * j;
    if (co < 27)
      om_part[(((size_t)split * NB + b) * 27 + co) * HW + h * 64 + w] = acc[j];
  }
}

// ---------------- sampling metadata: per (b,k,hw): 4 tap weights (mask*valid folded) + 4 clipped indices
__global__ __launch_bounds__(256) void k_prep_md(
    const float* __restrict__ om_part, const float* __restrict__ b_off,
    float4* __restrict__ md_w, int4* __restrict__ md_i)
{
  int t = blockIdx.x * 256 + threadIdx.x;
  if (t >= NB * 9 * HW) return;
  int hw = t & 4095;
  int bk = t >> 12;
  int k = bk % 9;
  int b = bk / 9;
  int h = hw >> 6, w = hw & 63;

  float dy = b_off[2 * k], dx = b_off[2 * k + 1], mr = b_off[18 + k];
#pragma unroll
  for (int s = 0; s < OCSPLIT; ++s) {
    size_t o = ((size_t)s * NB + b) * 27 * HW + hw;
    dy += om_part[o + (size_t)(2 * k) * HW];
    dx += om_part[o + (size_t)(2 * k + 1) * HW];
    mr += om_part[o + (size_t)(18 + k) * HW];
  }
  float m = 1.0f / (1.0f + expf(-mr));

  int ky = k / 3 - 1, kx = k % 3 - 1;
  float py = dy + (float)h + (float)ky;
  float px = dx + (float)w + (float)kx;
  float y0f = floorf(py), x0f = floorf(px);
  float fy = py - y0f, fx = px - x0f;
  int y0 = (int)y0f, x0 = (int)x0f;
  int y1 = y0 + 1, x1 = x0 + 1;

  bool vy0 = (y0 >= 0) & (y0 < 64), vy1 = (y1 >= 0) & (y1 < 64);
  bool vx0 = (x0 >= 0) & (x0 < 64), vx1 = (x1 >= 0) & (x1 < 64);
  int cy0 = min(max(y0, 0), 63), cy1 = min(max(y1, 0), 63);
  int cx0 = min(max(x0, 0), 63), cx1 = min(max(x1, 0), 63);

  float4 wv;
  wv.x = (vy0 && vx0) ? (1.f - fy) * (1.f - fx) * m : 0.f;
  wv.y = (vy0 && vx1) ? (1.f - fy) * fx * m : 0.f;
  wv.z = (vy1 && vx0) ? fy * (1.f - fx) * m : 0.f;
  wv.w = (vy1 && vx1) ? fy * fx * m : 0.f;
  int4 iv;
  iv.x = cy0 * 64 + cx0;
  iv.y = cy0 * 64 + cx1;
  iv.z = cy1 * 64 + cx0;
  iv.w = cy1 * 64 + cx1;
  md_w[t] = wv;
  md_i[t] = iv;
}

// ---------------- fused DCN gather + einsum + bias/BN + ReLU
// block: 32 positions of one b, all 128 Cout. thread: 8 co x 2 pos accumulators.
__global__ __launch_bounds__(256) void k_dcn(
    const float* __restrict__ x, const float* __restrict__ w_t,
    const float* __restrict__ bias_t,
    const float4* __restrict__ md_w, const int4* __restrict__ md_i,
    float* __restrict__ y)
{
  int blk = blockIdx.x;            // 512 blocks
  int b = blk >> 7;
  int p0 = (blk & 127) * 32;
  int t = threadIdx.x;

  __shared__ __align__(16) float wlds[1600];
  __shared__ __align__(16) float slds[9 * 32];
  __shared__ float bl[COUT];

  // load this thread's sampling metadata into registers (reused for all 256 channels)
  int k0 = t >> 5, ppos = t & 31;
  size_t mdbase = (size_t)b * 9 * HW;
  float4 mw0 = md_w[mdbase + (size_t)k0 * HW + p0 + ppos];
  int4  mi0 = md_i[mdbase + (size_t)k0 * HW + p0 + ppos];
  float4 mw1; int4 mi1;
  bool has2 = (t < 32);
  if (has2) {
    mw1 = md_w[mdbase + (size_t)8 * HW + p0 + t];
    mi1 = md_i[mdbase + (size_t)8 * HW + p0 + t];
  }
  if (t < COUT) bl[t] = bias_t[t];

  int cog = t & 15;     // 16 groups x 8 co
  int posg = t >> 4;    // 16 groups x 2 pos

  float2 acc[8];
#pragma unroll
  for (int j = 0; j < 8; ++j) { acc[j].x = 0.f; acc[j].y = 0.f; }

  const float* xb = x + (size_t)b * CIN * HW;

  for (int c = 0; c < CIN; ++c) {
    __syncthreads();
    { // stage scaled weights: 1600 floats = 400 float4
      const float4* wsrc = (const float4*)(w_t + (size_t)c * 1600);
      ((float4*)wlds)[t] = wsrc[t];
      if (t < 144) ((float4*)wlds)[256 + t] = wsrc[256 + t];
    }
    { // gather deformable samples for this channel
      const float* xc = xb + (size_t)c * HW;
      float s0 = mw0.x * xc[mi0.x] + mw0.y * xc[mi0.y] +
                 mw0.z * xc[mi0.z] + mw0.w * xc[mi0.w];
      slds[t] = s0;
      if (has2) {
        float s1 = mw1.x * xc[mi1.x] + mw1.y * xc[mi1.y] +
                   mw1.z * xc[mi1.z] + mw1.w * xc[mi1.w];
        slds[256 + t] = s1;
      }
    }
    __syncthreads();

    float2 sv[9];
#pragma unroll
    for (int k = 0; k < 9; ++k)
      sv[k] = *(const float2*)&slds[k * 32 + posg * 2];

#pragma unroll
    for (int co = 0; co < 8; ++co) {
      const float* wp = &wlds[cog * 100 + co * 12];
      float4 wa = *(const float4*)(wp);
      float4 wb = *(const float4*)(wp + 4);
      float w8 = wp[8];
      acc[co].x = fmaf(wa.x, sv[0].x, acc[co].x); acc[co].y = fmaf(wa.x, sv[0].y, acc[co].y);
      acc[co].x = fmaf(wa.y, sv[1].x, acc[co].x); acc[co].y = fmaf(wa.y, sv[1].y, acc[co].y);
      acc[co].x = fmaf(wa.z, sv[2].x, acc[co].x); acc[co].y = fmaf(wa.z, sv[2].y, acc[co].y);
      acc[co].x = fmaf(wa.w, sv[3].x, acc[co].x); acc[co].y = fmaf(wa.w, sv[3].y, acc[co].y);
      acc[co].x = fmaf(wb.x, sv[4].x, acc[co].x); acc[co].y = fmaf(wb.x, sv[4].y, acc[co].y);
      acc[co].x = fmaf(wb.y, sv[5].x, acc[co].x); acc[co].y = fmaf(wb.y, sv[5].y, acc[co].y);
      acc[co].x = fmaf(wb.z, sv[6].x, acc[co].x); acc[co].y = fmaf(wb.z, sv[6].y, acc[co].y);
      acc[co].x = fmaf(wb.w, sv[7].x, acc[co].x); acc[co].y = fmaf(wb.w, sv[7].y, acc[co].y);
      acc[co].x = fmaf(w8,   sv[8].x, acc[co].x); acc[co].y = fmaf(w8,   sv[8].y, acc[co].y);
    }
  }

  // epilogue: bias + relu, write y (pre-upsample activation)
#pragma unroll
  for (int co = 0; co < 8; ++co) {
    int coa = cog * 8 + co;
    float bv = bl[coa];
    float2 v;
    v.x = fmaxf(acc[co].x + bv, 0.f);
    v.y = fmaxf(acc[co].y + bv, 0.f);
    *(float2*)&y[((size_t)b * COUT + coa) * HW + p0 + posg * 2] = v;
  }
}

// ---------------- 2x bilinear upsample, align_corners
__global__ __launch_bounds__(256) void k_up(const float* __restrict__ y, float* __restrict__ out)
{
  int t = blockIdx.x * 256 + threadIdx.x;
  if (t >= NB * COUT * 128 * 128) return;
  int j = t & 127;
  int i = (t >> 7) & 127;
  int bc = t >> 14;
  const float R = (float)(63.0 / 127.0);
  float pi = (float)i * R;
  float pj = (float)j * R;
  float i0f = floorf(pi), j0f = floorf(pj);
  int i0 = (int)i0f, j0 = (int)j0f;
  int i1 = min(i0 + 1, 63), j1 = min(j0 + 1, 63);
  float f = pi - i0f, g = pj - j0f;
  const float* yb = y + (size_t)bc * HW;
  float a  = yb[i0 * 64 + j0];
  float bb = yb[i0 * 64 + j1];
  float cc = yb[i1 * 64 + j0];
  float dd = yb[i1 * 64 + j1];
  float t0 = a * (1.f - f) + cc * f;   // column j0, rows interpolated first
  float t1 = bb * (1.f - f) + dd * f;  // column j1
  out[t] = t0 * (1.f - g) + t1 * g;
}

extern "C" void kernel_launch(void* const* d_in, const int* in_sizes, int n_in,
                              void* d_out, int out_size, void* d_ws, size_t ws_size,
                              hipStream_t stream)
{
  const float* x     = (const float*)d_in[0];
  const float* w_off = (const float*)d_in[1];
  const float* b_off = (const float*)d_in[2];
  const float* w_dcn = (const float*)d_in[3];
  const float* b_dcn = (const float*)d_in[4];
  const float* gamma = (const float*)d_in[5];
  const float* beta  = (const float*)d_in[6];
  const float* rmean = (const float*)d_in[7];
  const float* rvar  = (const float*)d_in[8];
  float* out = (float*)d_out;

  char* ws = (char*)d_ws;
  size_t off = 0;
  auto alloc = [&](size_t bytes) {
    void* p = ws + off;
    off = (off + bytes + 255) & ~255UL;
    return p;
  };
  float*  om_part = (float*) alloc(sizeof(float)  * OCSPLIT * NB * 27 * HW);
  float4* md_w    = (float4*)alloc(sizeof(float4) * NB * 9 * HW);
  int4*   md_i    = (int4*)  alloc(sizeof(int4)   * NB * 9 * HW);
  float*  w_t     = (float*) alloc(sizeof(float)  * CIN * 1600);
  float*  bias_t  = (float*) alloc(sizeof(float)  * COUT);
  float*  ybuf    = (float*) alloc(sizeof(float)  * NB * COUT * HW);
  (void)ws_size;

  k_prep_w<<<(CIN * COUT * 9 + 255) / 256, 256, 0, stream>>>(
      w_dcn, b_dcn, gamma, beta, rmean, rvar, w_t, bias_t);
  k_off_conv<<<NB * HH * OCSPLIT, 256, 0, stream>>>(x, w_off, om_part);
  k_prep_md<<<(NB * 9 * HW + 255) / 256, 256, 0, stream>>>(om_part, b_off, md_w, md_i);
  k_dcn<<<NB * (HW / 32), 256, 0, stream>>>(x, w_t, bias_t, md_w, md_i, ybuf);
  k_up<<<(NB * COUT * 128 * 128 + 255) / 256, 256, 0, stream>>>(ybuf, out);
}

// Round 3
// 311.203 us; speedup vs baseline: 1.7344x; 1.7344x over previous
//
#include <hip/hip_runtime.h>
#include <math.h>

#define CIN  256
#define COUT 128
#define HW   4096
#define NB   4
#define OCSPLIT 4
#define CSPLIT  4
#define CPC  (CIN / CSPLIT)   // 64 channels per k_dcn block

// ---------------- weight prep: w_t[c][co_grp*100 + co_in*12 + k] = w_dcn[co][c][k] * bn_scale[co]
__global__ __launch_bounds__(256) void k_prep_w(
    const float* __restrict__ w_dcn, const float* __restrict__ b_dcn,
    const float* __restrict__ gamma, const float* __restrict__ beta,
    const float* __restrict__ rmean, const float* __restrict__ rvar,
    float* __restrict__ w_t, float* __restrict__ bias_t)
{
  int t = blockIdx.x * 256 + threadIdx.x;
  if (t < COUT) {
    float sc = gamma[t] * rsqrtf(rvar[t] + 1e-5f);
    bias_t[t] = b_dcn[t] * sc + beta[t] - rmean[t] * sc;
  }
  if (t >= CIN * COUT * 9) return;
  int k = t % 9;
  int q = t / 9;
  int co = q % COUT;
  int c  = q / COUT;
  float sc = gamma[co] * rsqrtf(rvar[co] + 1e-5f);
  w_t[(size_t)c * 1600 + (co >> 3) * 100 + (co & 7) * 12 + k] =
      w_dcn[((size_t)co * CIN + c) * 9 + k] * sc;
}

// ---------------- offset conv (27 ch, 3x3, pad 1), split over ci into OCSPLIT partials
__global__ __launch_bounds__(256) void k_off_conv(
    const float* __restrict__ x, const float* __restrict__ w_off,
    float* __restrict__ om_part)
{
  int blk = blockIdx.x;
  int split = blk & (OCSPLIT - 1);
  int bh = blk / OCSPLIT;
  int b = bh >> 6, h = bh & 63;
  int ci0 = split * (CIN / OCSPLIT);

  __shared__ float xs[8][3][66];
  __shared__ float wl[8][27][9];

  int t = threadIdx.x;
  int w = t & 63;
  int slot = t >> 6;

  float acc[7];
#pragma unroll
  for (int j = 0; j < 7; ++j) acc[j] = 0.f;

  const int NT = (CIN / OCSPLIT) / 8;
  for (int tile = 0; tile < NT; ++tile) {
    int cb = ci0 + tile * 8;
    __syncthreads();
    for (int j = t; j < 8 * 3 * 66; j += 256) {
      int ci = j / 198, rem = j - ci * 198;
      int r = rem / 66, wp = rem - r * 66;
      int hh = h + r - 1, ww = wp - 1;
      float v = 0.f;
      if (hh >= 0 && hh < 64 && (unsigned)ww < 64u)
        v = x[(((size_t)b * CIN + cb + ci) * 64 + hh) * 64 + ww];
      xs[ci][r][wp] = v;
    }
    for (int j = t; j < 8 * 27 * 9; j += 256) {
      int ci = j / 243, rem = j - ci * 243;
      int c2 = rem / 9, k = rem - c2 * 9;
      wl[ci][c2][k] = w_off[((size_t)c2 * CIN + cb + ci) * 9 + k];
    }
    __syncthreads();
#pragma unroll 1
    for (int ci = 0; ci < 8; ++ci) {
      float xv[3][3];
#pragma unroll
      for (int r = 0; r < 3; ++r)
#pragma unroll
        for (int d = 0; d < 3; ++d)
          xv[r][d] = xs[ci][r][w + d];
#pragma unroll
      for (int j = 0; j < 7; ++j) {
        int co = slot + 4 * j;
        if (co < 27) {
#pragma unroll
          for (int r = 0; r < 3; ++r)
#pragma unroll
            for (int d = 0; d < 3; ++d)
              acc[j] = fmaf(wl[ci][co][r * 3 + d], xv[r][d], acc[j]);
        }
      }
    }
  }
#pragma unroll
  for (int j = 0; j < 7; ++j) {
    int co = slot + 4 * j;
    if (co < 27)
      om_part[(((size_t)split * NB + b) * 27 + co) * HW + h * 64 + w] = acc[j];
  }
}

// ---------------- sampling metadata
__global__ __launch_bounds__(256) void k_prep_md(
    const float* __restrict__ om_part, const float* __restrict__ b_off,
    float4* __restrict__ md_w, int4* __restrict__ md_i)
{
  int t = blockIdx.x * 256 + threadIdx.x;
  if (t >= NB * 9 * HW) return;
  int hw = t & 4095;
  int bk = t >> 12;
  int k = bk % 9;
  int b = bk / 9;
  int h = hw >> 6, w = hw & 63;

  float dy = b_off[2 * k], dx = b_off[2 * k + 1], mr = b_off[18 + k];
#pragma unroll
  for (int s = 0; s < OCSPLIT; ++s) {
    size_t o = ((size_t)s * NB + b) * 27 * HW + hw;
    dy += om_part[o + (size_t)(2 * k) * HW];
    dx += om_part[o + (size_t)(2 * k + 1) * HW];
    mr += om_part[o + (size_t)(18 + k) * HW];
  }
  float m = 1.0f / (1.0f + expf(-mr));

  int ky = k / 3 - 1, kx = k % 3 - 1;
  float py = dy + (float)h + (float)ky;
  float px = dx + (float)w + (float)kx;
  float y0f = floorf(py), x0f = floorf(px);
  float fy = py - y0f, fx = px - x0f;
  int y0 = (int)y0f, x0 = (int)x0f;
  int y1 = y0 + 1, x1 = x0 + 1;

  bool vy0 = (y0 >= 0) & (y0 < 64), vy1 = (y1 >= 0) & (y1 < 64);
  bool vx0 = (x0 >= 0) & (x0 < 64), vx1 = (x1 >= 0) & (x1 < 64);
  int cy0 = min(max(y0, 0), 63), cy1 = min(max(y1, 0), 63);
  int cx0 = min(max(x0, 0), 63), cx1 = min(max(x1, 0), 63);

  float4 wv;
  wv.x = (vy0 && vx0) ? (1.f - fy) * (1.f - fx) * m : 0.f;
  wv.y = (vy0 && vx1) ? (1.f - fy) * fx * m : 0.f;
  wv.z = (vy1 && vx0) ? fy * (1.f - fx) * m : 0.f;
  wv.w = (vy1 && vx1) ? fy * fx * m : 0.f;
  int4 iv;
  iv.x = cy0 * 64 + cx0;
  iv.y = cy0 * 64 + cx1;
  iv.z = cy1 * 64 + cx0;
  iv.w = cy1 * 64 + cx1;
  md_w[t] = wv;
  md_i[t] = iv;
}

// ---------------- fused DCN gather + partial einsum (channel-split, prefetched, dbuf LDS)
// grid: CSPLIT x NB x 128 ptiles. block: 32 positions x 128 Cout, 64 channels.
__global__ __launch_bounds__(256, 4) void k_dcn(
    const float* __restrict__ x, const float* __restrict__ w_t,
    const float4* __restrict__ md_w, const int4* __restrict__ md_i,
    float* __restrict__ part)
{
  int blk = blockIdx.x;
  int ptile = blk & 127;
  int b = (blk >> 7) & (NB - 1);
  int s4 = blk >> 9;
  int p0 = ptile * 32;
  int c0 = s4 * CPC;
  int t = threadIdx.x;

  __shared__ __align__(16) float wlds[2][1600];
  __shared__ __align__(16) float slds[2][288];

  // sampling metadata in registers (channel-invariant)
  int k0 = t >> 5, ppos = t & 31;
  size_t mdbase = (size_t)b * 9 * HW;
  float4 mw0 = md_w[mdbase + (size_t)k0 * HW + p0 + ppos];
  int4  mi0 = md_i[mdbase + (size_t)k0 * HW + p0 + ppos];
  float4 mw1; int4 mi1;
  bool has2 = (t < 32);
  if (has2) {
    mw1 = md_w[mdbase + (size_t)8 * HW + p0 + t];
    mi1 = md_i[mdbase + (size_t)8 * HW + p0 + t];
  }

  int cog = t & 15;
  int posg = t >> 4;

  float2 acc[8];
#pragma unroll
  for (int j = 0; j < 8; ++j) { acc[j].x = 0.f; acc[j].y = 0.f; }

  const float* xb = x + (size_t)b * CIN * HW;

  // prefetch channel c0
  const float4* wsrc = (const float4*)(w_t + (size_t)c0 * 1600);
  const float* xc = xb + (size_t)c0 * HW;
  float4 wn0 = wsrc[t];
  float4 wn1 = (t < 144) ? wsrc[256 + t] : make_float4(0.f, 0.f, 0.f, 0.f);
  float ga = xc[mi0.x], gb = xc[mi0.y], gc = xc[mi0.z], gd = xc[mi0.w];
  float ha = 0.f, hb = 0.f, hc = 0.f, hd = 0.f;
  if (has2) { ha = xc[mi1.x]; hb = xc[mi1.y]; hc = xc[mi1.z]; hd = xc[mi1.w]; }

  for (int c = 0; c < CPC; ++c) {
    int p = c & 1;
    // write staged data for channel c from prefetch registers
    ((float4*)wlds[p])[t] = wn0;
    if (t < 144) ((float4*)wlds[p])[256 + t] = wn1;
    slds[p][t] = mw0.x * ga + mw0.y * gb + mw0.z * gc + mw0.w * gd;
    if (has2)
      slds[p][256 + t] = mw1.x * ha + mw1.y * hb + mw1.z * hc + mw1.w * hd;

    // issue prefetch for channel c+1 (overlaps barrier + FMA phase)
    int nc = c + 1 < CPC ? c + 1 : c;
    const float4* wn = (const float4*)(w_t + (size_t)(c0 + nc) * 1600);
    const float* xn = xb + (size_t)(c0 + nc) * HW;
    wn0 = wn[t];
    if (t < 144) wn1 = wn[256 + t];
    ga = xn[mi0.x]; gb = xn[mi0.y]; gc = xn[mi0.z]; gd = xn[mi0.w];
    if (has2) { ha = xn[mi1.x]; hb = xn[mi1.y]; hc = xn[mi1.z]; hd = xn[mi1.w]; }

    __syncthreads();

    float2 sv[9];
#pragma unroll
    for (int k = 0; k < 9; ++k)
      sv[k] = *(const float2*)&slds[p][k * 32 + posg * 2];

#pragma unroll
    for (int co = 0; co < 8; ++co) {
      const float* wp = &wlds[p][cog * 100 + co * 12];
      float4 wa = *(const float4*)(wp);
      float4 wb = *(const float4*)(wp + 4);
      float w8 = wp[8];
      acc[co].x = fmaf(wa.x, sv[0].x, acc[co].x); acc[co].y = fmaf(wa.x, sv[0].y, acc[co].y);
      acc[co].x = fmaf(wa.y, sv[1].x, acc[co].x); acc[co].y = fmaf(wa.y, sv[1].y, acc[co].y);
      acc[co].x = fmaf(wa.z, sv[2].x, acc[co].x); acc[co].y = fmaf(wa.z, sv[2].y, acc[co].y);
      acc[co].x = fmaf(wa.w, sv[3].x, acc[co].x); acc[co].y = fmaf(wa.w, sv[3].y, acc[co].y);
      acc[co].x = fmaf(wb.x, sv[4].x, acc[co].x); acc[co].y = fmaf(wb.x, sv[4].y, acc[co].y);
      acc[co].x = fmaf(wb.y, sv[5].x, acc[co].x); acc[co].y = fmaf(wb.y, sv[5].y, acc[co].y);
      acc[co].x = fmaf(wb.z, sv[6].x, acc[co].x); acc[co].y = fmaf(wb.z, sv[6].y, acc[co].y);
      acc[co].x = fmaf(wb.w, sv[7].x, acc[co].x); acc[co].y = fmaf(wb.w, sv[7].y, acc[co].y);
      acc[co].x = fmaf(w8,   sv[8].x, acc[co].x); acc[co].y = fmaf(w8,   sv[8].y, acc[co].y);
    }
  }

  // write fp32 partials (bias/relu applied in k_reduce)
#pragma unroll
  for (int co = 0; co < 8; ++co) {
    int coa = cog * 8 + co;
    *(float2*)&part[(((size_t)s4 * NB + b) * COUT + coa) * HW + p0 + posg * 2] = acc[co];
  }
}

// ---------------- reduce partials + bias + relu
__global__ __launch_bounds__(256) void k_reduce(
    const float* __restrict__ part, const float* __restrict__ bias_t,
    float* __restrict__ y)
{
  const int N4 = NB * COUT * HW / 4;
  int t = blockIdx.x * 256 + threadIdx.x;
  if (t >= N4) return;
  int base = t * 4;
  int co = (base / HW) & (COUT - 1);
  float4 v = *(const float4*)&part[base];
#pragma unroll
  for (int s = 1; s < CSPLIT; ++s) {
    float4 u = *(const float4*)&part[(size_t)s * (NB * COUT * HW) + base];
    v.x += u.x; v.y += u.y; v.z += u.z; v.w += u.w;
  }
  float bv = bias_t[co];
  v.x = fmaxf(v.x + bv, 0.f);
  v.y = fmaxf(v.y + bv, 0.f);
  v.z = fmaxf(v.z + bv, 0.f);
  v.w = fmaxf(v.w + bv, 0.f);
  *(float4*)&y[base] = v;
}

// ---------------- 2x bilinear upsample, align_corners
__global__ __launch_bounds__(256) void k_up(const float* __restrict__ y, float* __restrict__ out)
{
  int t = blockIdx.x * 256 + threadIdx.x;
  if (t >= NB * COUT * 128 * 128) return;
  int j = t & 127;
  int i = (t >> 7) & 127;
  int bc = t >> 14;
  const float R = (float)(63.0 / 127.0);
  float pi = (float)i * R;
  float pj = (float)j * R;
  float i0f = floorf(pi), j0f = floorf(pj);
  int i0 = (int)i0f, j0 = (int)j0f;
  int i1 = min(i0 + 1, 63), j1 = min(j0 + 1, 63);
  float f = pi - i0f, g = pj - j0f;
  const float* yb = y + (size_t)bc * HW;
  float a  = yb[i0 * 64 + j0];
  float bb = yb[i0 * 64 + j1];
  float cc = yb[i1 * 64 + j0];
  float dd = yb[i1 * 64 + j1];
  float t0 = a * (1.f - f) + cc * f;
  float t1 = bb * (1.f - f) + dd * f;
  out[t] = t0 * (1.f - g) + t1 * g;
}

extern "C" void kernel_launch(void* const* d_in, const int* in_sizes, int n_in,
                              void* d_out, int out_size, void* d_ws, size_t ws_size,
                              hipStream_t stream)
{
  const float* x     = (const float*)d_in[0];
  const float* w_off = (const float*)d_in[1];
  const float* b_off = (const float*)d_in[2];
  const float* w_dcn = (const float*)d_in[3];
  const float* b_dcn = (const float*)d_in[4];
  const float* gamma = (const float*)d_in[5];
  const float* beta  = (const float*)d_in[6];
  const float* rmean = (const float*)d_in[7];
  const float* rvar  = (const float*)d_in[8];
  float* out = (float*)d_out;

  char* ws = (char*)d_ws;
  size_t off = 0;
  auto alloc = [&](size_t bytes) {
    void* p = ws + off;
    off = (off + bytes + 255) & ~255UL;
    return p;
  };
  float*  om_part = (float*) alloc(sizeof(float)  * OCSPLIT * NB * 27 * HW);
  float4* md_w    = (float4*)alloc(sizeof(float4) * NB * 9 * HW);
  int4*   md_i    = (int4*)  alloc(sizeof(int4)   * NB * 9 * HW);
  float*  w_t     = (float*) alloc(sizeof(float)  * CIN * 1600);
  float*  bias_t  = (float*) alloc(sizeof(float)  * COUT);
  float*  ybuf    = (float*) alloc(sizeof(float)  * NB * COUT * HW);
  float*  part    = (float*) alloc(sizeof(float)  * CSPLIT * NB * COUT * HW);
  (void)ws_size;

  k_prep_w<<<(CIN * COUT * 9 + 255) / 256, 256, 0, stream>>>(
      w_dcn, b_dcn, gamma, beta, rmean, rvar, w_t, bias_t);
  k_off_conv<<<NB * 64 * OCSPLIT, 256, 0, stream>>>(x, w_off, om_part);
  k_prep_md<<<(NB * 9 * HW + 255) / 256, 256, 0, stream>>>(om_part, b_off, md_w, md_i);
  k_dcn<<<CSPLIT * NB * 128, 256, 0, stream>>>(x, w_t, md_w, md_i, part);
  k_reduce<<<(NB * COUT * HW / 4 + 255) / 256, 256, 0, stream>>>(part, bias_t, ybuf);
  k_up<<<(NB * COUT * 128 * 128 + 255) / 256, 256, 0, stream>>>(ybuf, out);
}